// Round 3
// baseline (256.953 us; speedup 1.0000x reference)
//
#include <hip/hip_runtime.h>

#define NN 4
#define CC 20
#define HH 64
#define WW 2048
#define CG 4           // channel groups
#define CPG (CC / CG)  // 5 channels per group
#define PX 4           // pixels per thread

// R2 body unchanged (VGPR=64, no spills, XCD-affinity swizzle).
// Single change: __launch_bounds__(256,4) -> (256,8).
// 64 VGPR is exactly the 8-waves/SIMD boundary, so the register file
// supports 32 waves/CU; (256,8) lets 8 blocks/CU reside -> all 2048
// blocks co-resident in ONE tranche (256 CU x 8), doubling the
// latency-hiding wave pool for this latency-bound kernel.
__global__ __launch_bounds__(256, 8) void lc_xyz_kernel(
    const float* __restrict__ xyz,
    const float* __restrict__ softmax,
    const int* __restrict__ mask,
    float* __restrict__ out)
{
    const unsigned id  = blockIdx.x;            // 0..2047
    const unsigned xcd = id & 7u;               // round-robin XCD slot
    const unsigned v   = xcd * 256u + (id >> 3); // contiguous chunk per XCD
    // v = x + 2*h + 128*z  (z-major: each XCD gets z in {2*xcd, 2*xcd+1})
    const int xhalf = (int)(v & 1u);
    const int h     = (int)((v >> 1) & 63u);
    const int z     = (int)(v >> 7);            // 0..15
    const int n     = z >> 2;
    const int cg    = z & 3;

    const int t  = xhalf * 256 + (int)threadIdx.x;  // pixel-quad index in row: 0..511
    const int hw = HH * WW;
    const int p0 = t * PX;

    const float* xb  = xyz     + (size_t)n * 3  * hw;
    const float* smb = softmax + (size_t)n * CC * hw + (size_t)(cg * CPG) * hw;
    const int*   mb  = mask    + (size_t)n * hw;

    const int ctr = h * WW + p0;
    const float4 cxv = *(const float4*)(xb + 0 * hw + ctr);
    const float4 cyv = *(const float4*)(xb + 1 * hw + ctr);
    const float4 czv = *(const float4*)(xb + 2 * hw + ctr);
    const float cx[PX] = {cxv.x, cxv.y, cxv.z, cxv.w};
    const float cy[PX] = {cyv.x, cyv.y, cyv.z, cyv.w};
    const float cz[PX] = {czv.x, czv.y, czv.z, czv.w};

    float acc[CPG][PX];
#pragma unroll
    for (int c = 0; c < CPG; ++c)
#pragma unroll
        for (int i = 0; i < PX; ++i) acc[c][i] = 0.f;

    // Window indices j=0..11 map to w = p0-4+j; taps use j = i+dx+2 in [2,9].
    // Aligned 16B chunks at p0-4, p0, p0+4; edge chunks clamped (their taps
    // are zeroed via validity, and all VALID taps come from unclamped chunks).
    int c0 = p0 - 4; if (c0 < 0) c0 = 0;
    const int c1 = p0;
    int c2 = p0 + 4; if (c2 > WW - 4) c2 = WW - 4;

    float vf[12];
#pragma unroll
    for (int j = 2; j <= 9; ++j)
        vf[j] = ((unsigned)(p0 - 4 + j) < (unsigned)WW) ? 1.f : 0.f;

#pragma unroll
    for (int dy = -2; dy <= 2; ++dy) {
        const int row = h + dy;
        if ((unsigned)row >= (unsigned)HH) continue;   // wave-uniform
        const int rb = row * WW;

        // Batched independent row loads: 3 int4 + 9 float4.
        const int4 m0 = *(const int4*)(mb + rb + c0);
        const int4 m1 = *(const int4*)(mb + rb + c1);
        const int4 m2 = *(const int4*)(mb + rb + c2);
        const float4 x0 = *(const float4*)(xb + 0 * hw + rb + c0);
        const float4 x1 = *(const float4*)(xb + 0 * hw + rb + c1);
        const float4 x2 = *(const float4*)(xb + 0 * hw + rb + c2);
        const float4 y0 = *(const float4*)(xb + 1 * hw + rb + c0);
        const float4 y1 = *(const float4*)(xb + 1 * hw + rb + c1);
        const float4 y2 = *(const float4*)(xb + 1 * hw + rb + c2);
        const float4 z0 = *(const float4*)(xb + 2 * hw + rb + c0);
        const float4 z1 = *(const float4*)(xb + 2 * hw + rb + c1);
        const float4 z2 = *(const float4*)(xb + 2 * hw + rb + c2);

        const float xw[12] = {x0.x,x0.y,x0.z,x0.w, x1.x,x1.y,x1.z,x1.w, x2.x,x2.y,x2.z,x2.w};
        const float yw[12] = {y0.x,y0.y,y0.z,y0.w, y1.x,y1.y,y1.z,y1.w, y2.x,y2.y,y2.z,y2.w};
        const float zw[12] = {z0.x,z0.y,z0.z,z0.w, z1.x,z1.y,z1.z,z1.w, z2.x,z2.y,z2.z,z2.w};
        const int   mi[12] = {m0.x,m0.y,m0.z,m0.w, m1.x,m1.y,m1.z,m1.w, m2.x,m2.y,m2.z,m2.w};

        float mf[12];
#pragma unroll
        for (int j = 2; j <= 9; ++j) mf[j] = vf[j] * (float)mi[j];

        // Gaussian weights, once per (pixel, tap), shared across channels.
        float g[PX][5];
#pragma unroll
        for (int i = 0; i < PX; ++i) {
#pragma unroll
            for (int dx = 0; dx < 5; ++dx) {
                const int j = i + dx + 2;
                const float ax = xw[j] - cx[i];
                const float ay = yw[j] - cy[i];
                const float az = zw[j] - cz[i];
                const float d2 = ax * ax + ay * ay + az * az;
                g[i][dx] = mf[j] * __expf(-0.5f * d2);
            }
        }

        // Channel loop: 3 float4 loads + 20 FMA per channel.
#pragma unroll
        for (int c = 0; c < CPG; ++c) {
            const float* sp = smb + (size_t)c * hw + rb;
            const float4 s0 = *(const float4*)(sp + c0);
            const float4 s1 = *(const float4*)(sp + c1);
            const float4 s2 = *(const float4*)(sp + c2);
            const float sw[12] = {s0.x,s0.y,s0.z,s0.w, s1.x,s1.y,s1.z,s1.w, s2.x,s2.y,s2.z,s2.w};
#pragma unroll
            for (int i = 0; i < PX; ++i) {
                float a = acc[c][i];
#pragma unroll
                for (int dx = 0; dx < 5; ++dx)
                    a = fmaf(g[i][dx], sw[i + dx + 2], a);
                acc[c][i] = a;
            }
        }
    }

    float* ob = out + (size_t)n * CC * hw + (size_t)(cg * CPG) * hw + ctr;
#pragma unroll
    for (int c = 0; c < CPG; ++c)
        *(float4*)(ob + (size_t)c * hw) =
            make_float4(acc[c][0], acc[c][1], acc[c][2], acc[c][3]);
}

extern "C" void kernel_launch(void* const* d_in, const int* in_sizes, int n_in,
                              void* d_out, int out_size, void* d_ws, size_t ws_size,
                              hipStream_t stream) {
    const float* xyz     = (const float*)d_in[0];
    const float* softmax = (const float*)d_in[1];
    const int*   mask    = (const int*)d_in[2];
    float*       out     = (float*)d_out;

    dim3 block(256, 1, 1);
    dim3 grid((WW / (PX * 256)) * HH * (NN * CG), 1, 1);  // 2048 blocks, 1-D swizzled
    hipLaunchKernelGGL(lc_xyz_kernel, grid, block, 0, stream,
                       xyz, softmax, mask, out);
}

// Round 4
// 127.916 us; speedup vs baseline: 2.0088x; 2.0088x over previous
//
#include <hip/hip_runtime.h>

#define NN 4
#define CC 20
#define HH 64
#define WW 2048
#define CG 4           // channel groups
#define CPG (CC / CG)  // 5 channels per group
#define PX 4           // pixels per thread

// R0 proven config (3D grid, (256,4), no swizzle — 59us/dispatch) with ONE
// structural change: the 8-tap window [p0-2, p0+5] is loaded as TWO
// dword-aligned float4 loads at p0-2 / p0+2 (8B alignment is legal for
// dwordx4) instead of three 16B-aligned chunks. 27 -> 18 VMEM per row,
// window arrays 12 -> 8 floats. Edge threads (p0==0 / p0==WW-4) clamp the
// base and repair the always-valid center slots 2..5 via cndmask; outer
// slots 0,1,6,7 are zeroed through mf (their values never matter).
// VGPR tripwire: must stay <=64, WRITE_SIZE must stay 40960KB (R1/R3
// showed the spill cliff costs 2-3x).
__global__ __launch_bounds__(256, 4) void lc_xyz_kernel(
    const float* __restrict__ xyz,
    const float* __restrict__ softmax,
    const int* __restrict__ mask,
    float* __restrict__ out)
{
    const int t  = blockIdx.x * blockDim.x + threadIdx.x;  // pixel-quad index: 0..511
    const int h  = blockIdx.y;
    const int nz = blockIdx.z;
    const int n  = nz >> 2;
    const int cg = nz & 3;
    const int hw = HH * WW;
    const int p0 = t * PX;

    const float* xb  = xyz     + (size_t)n * 3  * hw;
    const float* smb = softmax + (size_t)n * CC * hw + (size_t)(cg * CPG) * hw;
    const int*   mb  = mask    + (size_t)n * hw;

    const int ctr = h * WW + p0;
    const float4 cxv = *(const float4*)(xb + 0 * hw + ctr);
    const float4 cyv = *(const float4*)(xb + 1 * hw + ctr);
    const float4 czv = *(const float4*)(xb + 2 * hw + ctr);
    const float cx[PX] = {cxv.x, cxv.y, cxv.z, cxv.w};
    const float cy[PX] = {cyv.x, cyv.y, cyv.z, cyv.w};
    const float cz[PX] = {czv.x, czv.y, czv.z, czv.w};

    float acc[CPG][PX];
#pragma unroll
    for (int c = 0; c < CPG; ++c)
#pragma unroll
        for (int i = 0; i < PX; ++i) acc[c][i] = 0.f;

    // Window slot j=0..7 holds position w = p0-2+j; tap (i,dx) uses j=i+dx.
    // Chunk A at a0=p0-2 covers j=0..3, chunk B at b0=p0+2 covers j=4..7.
    // Only the p0==0 thread clamps A (slots 2,3 then come from A.x,A.y);
    // only the p0==WW-4 thread clamps B (slots 4,5 from B.z,B.w).
    const int  a0 = p0 - 2;
    const int  b0 = p0 + 2;
    const bool sl = (a0 < 0);
    const bool sr = (b0 > WW - 4);
    const int  aC = sl ? 0 : a0;
    const int  bC = sr ? (WW - 4) : b0;
    const float vfL = sl ? 0.f : 1.f;   // validity of slots 0,1 (pos p0-2,p0-1)
    const float vfR = sr ? 0.f : 1.f;   // validity of slots 6,7 (pos p0+4,p0+5)

#pragma unroll
    for (int dy = -2; dy <= 2; ++dy) {
        const int row = h + dy;
        if ((unsigned)row >= (unsigned)HH) continue;   // wave-uniform
        const int rb = row * WW;

        // Batched independent row loads: 2 int4 + 6 float4.
        const int4   mA = *(const int4*)(mb + rb + aC);
        const int4   mB = *(const int4*)(mb + rb + bC);
        const float4 xA = *(const float4*)(xb + 0 * hw + rb + aC);
        const float4 xB = *(const float4*)(xb + 0 * hw + rb + bC);
        const float4 yA = *(const float4*)(xb + 1 * hw + rb + aC);
        const float4 yB = *(const float4*)(xb + 1 * hw + rb + bC);
        const float4 zA = *(const float4*)(xb + 2 * hw + rb + aC);
        const float4 zB = *(const float4*)(xb + 2 * hw + rb + bC);

        // Window values; slots 0,1,6,7 may hold clamped garbage (mf zeroes them).
        const float xw[8] = {xA.x, xA.y, sl ? xA.x : xA.z, sl ? xA.y : xA.w,
                             sr ? xB.z : xB.x, sr ? xB.w : xB.y, xB.z, xB.w};
        const float yw[8] = {yA.x, yA.y, sl ? yA.x : yA.z, sl ? yA.y : yA.w,
                             sr ? yB.z : yB.x, sr ? yB.w : yB.y, yB.z, yB.w};
        const float zw[8] = {zA.x, zA.y, sl ? zA.x : zA.z, sl ? zA.y : zA.w,
                             sr ? zB.z : zB.x, sr ? zB.w : zB.y, zB.z, zB.w};

        // Mask window: slots 2..5 are always-valid positions p0..p0+3,
        // slots 0,1 / 6,7 get the validity factor folded in.
        const float mf[8] = {
            vfL * (float)mA.x,
            vfL * (float)mA.y,
            (float)(sl ? mA.x : mA.z),
            (float)(sl ? mA.y : mA.w),
            (float)(sr ? mB.z : mB.x),
            (float)(sr ? mB.w : mB.y),
            vfR * (float)mB.z,
            vfR * (float)mB.w};

        // Gaussian weights, once per (pixel, tap), shared across channels.
        float g[PX][5];
#pragma unroll
        for (int i = 0; i < PX; ++i) {
#pragma unroll
            for (int dx = 0; dx < 5; ++dx) {
                const int j = i + dx;
                const float ax = xw[j] - cx[i];
                const float ay = yw[j] - cy[i];
                const float az = zw[j] - cz[i];
                const float d2 = ax * ax + ay * ay + az * az;
                g[i][dx] = mf[j] * __expf(-0.5f * d2);
            }
        }

        // Channel loop: 2 float4 loads + 20 FMA per channel.
#pragma unroll
        for (int c = 0; c < CPG; ++c) {
            const float* sp = smb + (size_t)c * hw + rb;
            const float4 sA = *(const float4*)(sp + aC);
            const float4 sB = *(const float4*)(sp + bC);
            const float sw[8] = {sA.x, sA.y, sl ? sA.x : sA.z, sl ? sA.y : sA.w,
                                 sr ? sB.z : sB.x, sr ? sB.w : sB.y, sB.z, sB.w};
#pragma unroll
            for (int i = 0; i < PX; ++i) {
                float a = acc[c][i];
#pragma unroll
                for (int dx = 0; dx < 5; ++dx)
                    a = fmaf(g[i][dx], sw[i + dx], a);
                acc[c][i] = a;
            }
        }
    }

    float* ob = out + (size_t)n * CC * hw + (size_t)(cg * CPG) * hw + ctr;
#pragma unroll
    for (int c = 0; c < CPG; ++c)
        *(float4*)(ob + (size_t)c * hw) =
            make_float4(acc[c][0], acc[c][1], acc[c][2], acc[c][3]);
}

extern "C" void kernel_launch(void* const* d_in, const int* in_sizes, int n_in,
                              void* d_out, int out_size, void* d_ws, size_t ws_size,
                              hipStream_t stream) {
    const float* xyz     = (const float*)d_in[0];
    const float* softmax = (const float*)d_in[1];
    const int*   mask    = (const int*)d_in[2];
    float*       out     = (float*)d_out;

    dim3 block(256, 1, 1);
    dim3 grid(WW / (PX * 256), HH, NN * CG);   // 2 x 64 x 16 = 2048 blocks
    hipLaunchKernelGGL(lc_xyz_kernel, grid, block, 0, stream,
                       xyz, softmax, mask, out);
}